// Round 1
// baseline (1006.809 us; speedup 1.0000x reference)
//
#include <hip/hip_runtime.h>

// ImplicitFunction MLP forward:
//   x = lrelu((points @ w0) * s0 + b0)           [N,3]->[N,64]
//   6x: x = lrelu((x @ wh[i]) * sh[i] + bh[i])   [N,64]->[N,64]
//   out = (x @ wo) * so + bo                     [N,64]->[N,1]
//
// Round 1: fp32 VALU baseline. One thread per point; activations in VGPRs;
// weight indices are wave-uniform so the compiler emits scalar (s_load)
// broadcasts -- no per-lane memory traffic for weights. 8-wide output
// blocking in the inner GEMV for ILP.

#define NEG_SLOPE 0.2f

__global__ __launch_bounds__(256) void mlp_fwd(
    const float* __restrict__ points,  // [N,3]
    const float* __restrict__ w0,      // [3,64]
    const float* __restrict__ s0,      // [64]
    const float* __restrict__ b0,      // [64]
    const float* __restrict__ wh,      // [6,64,64]
    const float* __restrict__ sh,      // [6,64]
    const float* __restrict__ bh,      // [6,64]
    const float* __restrict__ wo,      // [64,1]
    const float* __restrict__ so,      // scalar
    const float* __restrict__ bo,      // scalar
    float* __restrict__ out,           // [N,1]
    int n)
{
    const int p = blockIdx.x * blockDim.x + threadIdx.x;
    if (p >= n) return;

    const float c0 = points[3 * p + 0];
    const float c1 = points[3 * p + 1];
    const float c2 = points[3 * p + 2];

    float x[64];

    // ---- layer 0: [3]->[64] ----
#pragma unroll
    for (int j = 0; j < 64; ++j) {
        float a = fmaf(c0, w0[j], fmaf(c1, w0[64 + j], c2 * w0[128 + j]));
        a = fmaf(a, s0[j], b0[j]);
        x[j] = fmaxf(a, NEG_SLOPE * a);   // leaky relu (slope < 1)
    }

    // ---- 6 hidden layers: [64]->[64] ----
    for (int l = 0; l < 6; ++l) {
        const float* __restrict__ W = wh + (l << 12);  // [64,64] row-major (k-major)
        const float* __restrict__ S = sh + (l << 6);
        const float* __restrict__ B = bh + (l << 6);
        float y[64];
#pragma unroll
        for (int jb = 0; jb < 64; jb += 8) {
            float acc[8];
#pragma unroll
            for (int u = 0; u < 8; ++u) acc[u] = 0.f;
#pragma unroll
            for (int k = 0; k < 64; ++k) {
                const float xv = x[k];
#pragma unroll
                for (int u = 0; u < 8; ++u)
                    acc[u] = fmaf(xv, W[(k << 6) + jb + u], acc[u]);
            }
#pragma unroll
            for (int u = 0; u < 8; ++u) {
                float a = fmaf(acc[u], S[jb + u], B[jb + u]);
                y[jb + u] = fmaxf(a, NEG_SLOPE * a);
            }
        }
#pragma unroll
        for (int j = 0; j < 64; ++j) x[j] = y[j];
    }

    // ---- output layer: [64]->[1] ----
    float acc = 0.f;
#pragma unroll
    for (int k = 0; k < 64; ++k) acc = fmaf(x[k], wo[k], acc);
    out[p] = fmaf(acc, so[0], bo[0]);
}

extern "C" void kernel_launch(void* const* d_in, const int* in_sizes, int n_in,
                              void* d_out, int out_size, void* d_ws, size_t ws_size,
                              hipStream_t stream) {
    const float* points = (const float*)d_in[0];
    const float* w0     = (const float*)d_in[1];
    const float* s0     = (const float*)d_in[2];
    const float* b0     = (const float*)d_in[3];
    const float* wh     = (const float*)d_in[4];
    const float* sh     = (const float*)d_in[5];
    const float* bh     = (const float*)d_in[6];
    const float* wo     = (const float*)d_in[7];
    const float* so     = (const float*)d_in[8];
    const float* bo     = (const float*)d_in[9];
    float* out          = (float*)d_out;

    const int n = in_sizes[0] / 3;
    const int block = 256;
    const int grid = (n + block - 1) / block;
    mlp_fwd<<<grid, block, 0, stream>>>(points, w0, s0, b0, wh, sh, bh,
                                        wo, so, bo, out, n);
}

// Round 2
// 174.796 us; speedup vs baseline: 5.7599x; 5.7599x over previous
//
#include <hip/hip_runtime.h>

// ImplicitFunction MLP via fp16 MFMA (v_mfma_f32_32x32x16_f16).
//
// Math: carry activations scaled by 1/64 (x~ = x/64). lrelu is positively
// homogeneous, so hidden layers keep W unscaled and only bias is /64:
//   x~_{l+1} = lrelu(x~_l @ W' + b/64),  W' = W * s (scale folded)
// Layer 0: W0' = w0*s0/64, b0/64. Output: wo'' = wo*so*64, + bo.
// fp16 inputs, fp32 MFMA accumulate; rel err ~1e-3 << 2% threshold.
//
// GEMM orientation: C[m=feat_out][n=point] = A[m][k] * B[k][n],
// A = W'^T (per-lane fragments prearranged in ws, staged to LDS),
// B = activations^T. Per wave: 32 points, 2 M-tiles x 4 K-steps = 8 MFMAs/layer.
//
// Layouts (gfx950, 32x32x16):
//   A/B: lane (i=lane&31, h=lane>>5) holds k = 8h+j, j=0..7
//   C/D: col n = lane&31, row m = (r&3) + 8*(r>>2) + 4*(lane>>5), r=0..15
// C->next-B transition: lane (p,h)'s C values are exactly feats with
// (f>>2)&1 == h (quads of parity h). Next B-frag for K-step s needs quads
// (4s+2h, 4s+2h+1) -> one quad local, one from lane^32 -> shfl_xor(32).

typedef _Float16 half8 __attribute__((ext_vector_type(8)));
typedef float floatx16 __attribute__((ext_vector_type(16)));

#define N_HID 6
// ws byte offsets
#define OFF_A 0        // hidden weight frags: [6][t:2][s:4][lane:64][j:8] fp16 = 49152 B
#define OFF_B 49152    // layer0 A frags:      [t:2][lane:64][j:8] fp16      = 2048 B
#define OFF_C 51200    // biases/64 fp32:      [l:7][h:2][t:2][r:16]         = 1792 B
#define OFF_D 52992    // wo*so*64 fp32:       [h:2][t:2][r:16]              = 256 B
#define SETUP_TOTAL (24576 + 1024 + 448 + 64)
#define LDS_BYTES 51200   // regions A+B staged to LDS

__global__ __launch_bounds__(256) void setup_weights(
    const float* __restrict__ w0, const float* __restrict__ s0, const float* __restrict__ b0,
    const float* __restrict__ wh, const float* __restrict__ sh, const float* __restrict__ bh,
    const float* __restrict__ wo, const float* __restrict__ so,
    unsigned char* __restrict__ ws)
{
    int i = blockIdx.x * 256 + threadIdx.x;
    if (i < 24576) {
        // hidden weight fragments: A[m][k] = wh[l][k][m] * sh[l][m]
        int j = i & 7, lane = (i >> 3) & 63, s = (i >> 9) & 3, t = (i >> 11) & 1, l = i >> 12;
        int m = 32 * t + (lane & 31);
        int k = 16 * s + 8 * (lane >> 5) + j;
        ((_Float16*)(ws + OFF_A))[i] = (_Float16)(wh[(l * 64 + k) * 64 + m] * sh[l * 64 + m]);
    } else if (i < 24576 + 1024) {
        int i2 = i - 24576;
        int j = i2 & 7, lane = (i2 >> 3) & 63, t = i2 >> 9;
        int m = 32 * t + (lane & 31);
        int k = 8 * (lane >> 5) + j;
        float v = (k < 3) ? w0[k * 64 + m] * s0[m] * 0.015625f : 0.f;
        ((_Float16*)(ws + OFF_B))[i2] = (_Float16)v;
    } else if (i < 24576 + 1024 + 448) {
        int i2 = i - 24576 - 1024;
        int r = i2 & 15, t = (i2 >> 4) & 1, h = (i2 >> 5) & 1, l = i2 >> 6;
        int feat = 32 * t + (r & 3) + 8 * ((r >> 2) & 3) + 4 * h;
        float bv = (l == 0) ? b0[feat] : bh[(l - 1) * 64 + feat];
        ((float*)(ws + OFF_C))[i2] = bv * 0.015625f;
    } else if (i < SETUP_TOTAL) {
        int i2 = i - 24576 - 1024 - 448;
        int r = i2 & 15, t = (i2 >> 4) & 1, h = i2 >> 5;
        int feat = 32 * t + (r & 3) + 8 * ((r >> 2) & 3) + 4 * h;
        ((float*)(ws + OFF_D))[i2] = wo[feat] * so[0] * 64.f;
    }
}

union FragCast { int i[4]; half8 h; };

static __device__ __forceinline__ int pkrtz(float a, float b) {
    auto hh = __builtin_amdgcn_cvt_pkrtz(a, b);  // v2f16, RTZ pack
    int r;
    __builtin_memcpy(&r, &hh, 4);
    return r;
}

// bias add (fp32) + leaky relu -> xv[t][r]
static __device__ __forceinline__ void epilogue(
    const float4* __restrict__ biasBase, int l, int h,
    const floatx16& acc0, const floatx16& acc1, float xv[2][16])
{
    float4 bb[8];
    const float4* bp = biasBase + l * 16 + h * 8;
#pragma unroll
    for (int c = 0; c < 8; ++c) bb[c] = bp[c];
    const float* bf = (const float*)bb;  // flat idx t*16+r
#pragma unroll
    for (int t = 0; t < 2; ++t)
#pragma unroll
        for (int r = 0; r < 16; ++r) {
            float u = ((t == 0) ? acc0[r] : acc1[r]) + bf[t * 16 + r];
            xv[t][r] = fmaxf(u, 0.2f * u);
        }
}

__global__ __launch_bounds__(256, 3) void mlp_mfma(
    const float* __restrict__ points,
    const unsigned char* __restrict__ ws,
    const float* __restrict__ bo,
    float* __restrict__ out, int n)
{
    __shared__ __align__(16) unsigned char lds[LDS_BYTES];

    // stage weight fragments (regions A+B) to LDS
    {
        const uint4* src = (const uint4*)ws;
        uint4* dst = (uint4*)lds;
        for (int i = threadIdx.x; i < LDS_BYTES / 16; i += 256) dst[i] = src[i];
    }
    __syncthreads();

    const int lane = threadIdx.x & 63;
    const int wv = threadIdx.x >> 6;
    const int p = lane & 31;
    const int h = lane >> 5;
    const int ptRaw = (blockIdx.x * 4 + wv) * 32 + p;
    const int pt = (ptRaw < n) ? ptRaw : (n - 1);

    const float4* biasBase = (const float4*)(ws + OFF_C);
    float xv[2][16];

    // ---- layer 0: points (fp16, k=0..2 of K=16) ----
    {
        const float c0 = points[3 * pt + 0];
        const float c1 = points[3 * pt + 1];
        const float c2 = points[3 * pt + 2];
        FragCast z; z.i[0] = z.i[1] = z.i[2] = z.i[3] = 0;
        half8 bfr = z.h;
        if (h == 0) {
            bfr[0] = (_Float16)c0; bfr[1] = (_Float16)c1; bfr[2] = (_Float16)c2;
        }
        const half8* A0 = (const half8*)(lds + OFF_B);
        floatx16 acc0 = __builtin_amdgcn_mfma_f32_32x32x16_f16(A0[lane],      bfr, (floatx16)(0.0f), 0, 0, 0);
        floatx16 acc1 = __builtin_amdgcn_mfma_f32_32x32x16_f16(A0[64 + lane], bfr, (floatx16)(0.0f), 0, 0, 0);
        epilogue(biasBase, 0, h, acc0, acc1, xv);
    }

    // ---- 6 hidden layers ----
    for (int l = 0; l < N_HID; ++l) {
        // pack local quads: a = 4t + (r>>2); quad q = 2a + h (implicit)
        int L[8][2];
#pragma unroll
        for (int a = 0; a < 8; ++a) {
            const int t = a >> 2, rb = (a & 3) * 4;
            L[a][0] = pkrtz(xv[t][rb + 0], xv[t][rb + 1]);
            L[a][1] = pkrtz(xv[t][rb + 2], xv[t][rb + 3]);
        }
        int R[8][2];
#pragma unroll
        for (int a = 0; a < 8; ++a) {
            R[a][0] = __shfl_xor(L[a][0], 32);
            R[a][1] = __shfl_xor(L[a][1], 32);
        }
        // B-frag[s]: k = 16s + 8h + j needs quads (4s+2h, 4s+2h+1)
        half8 frag[4];
#pragma unroll
        for (int s = 0; s < 4; ++s) {
            FragCast u;
            u.i[0] = (h == 0) ? L[2 * s][0]     : R[2 * s + 1][0];
            u.i[1] = (h == 0) ? L[2 * s][1]     : R[2 * s + 1][1];
            u.i[2] = (h == 0) ? R[2 * s][0]     : L[2 * s + 1][0];
            u.i[3] = (h == 0) ? R[2 * s][1]     : L[2 * s + 1][1];
            frag[s] = u.h;
        }
        const half8* W = (const half8*)(lds + OFF_A) + l * 512 + lane;
        floatx16 acc0 = (floatx16)(0.0f), acc1 = (floatx16)(0.0f);
#pragma unroll
        for (int s = 0; s < 4; ++s) {
            acc0 = __builtin_amdgcn_mfma_f32_32x32x16_f16(W[s * 64],       frag[s], acc0, 0, 0, 0);
            acc1 = __builtin_amdgcn_mfma_f32_32x32x16_f16(W[256 + s * 64], frag[s], acc1, 0, 0, 0);
        }
        epilogue(biasBase, l + 1, h, acc0, acc1, xv);
    }

    // ---- output layer: per-lane partial dot + cross-half reduce ----
    {
        const float4* wop = (const float4*)(ws + OFF_D) + h * 8;
        float4 wv4[8];
#pragma unroll
        for (int c = 0; c < 8; ++c) wv4[c] = wop[c];
        const float* wf = (const float*)wv4;  // flat idx t*16+r
        float partial = 0.f;
#pragma unroll
        for (int t = 0; t < 2; ++t)
#pragma unroll
            for (int r = 0; r < 16; ++r)
                partial = fmaf(xv[t][r], wf[t * 16 + r], partial);
        partial += __shfl_xor(partial, 32);
        if (h == 0 && ptRaw < n) out[ptRaw] = partial + bo[0];
    }
}

extern "C" void kernel_launch(void* const* d_in, const int* in_sizes, int n_in,
                              void* d_out, int out_size, void* d_ws, size_t ws_size,
                              hipStream_t stream) {
    const float* points = (const float*)d_in[0];
    const float* w0     = (const float*)d_in[1];
    const float* s0     = (const float*)d_in[2];
    const float* b0     = (const float*)d_in[3];
    const float* wh     = (const float*)d_in[4];
    const float* sh     = (const float*)d_in[5];
    const float* bh     = (const float*)d_in[6];
    const float* wo     = (const float*)d_in[7];
    const float* so     = (const float*)d_in[8];
    const float* bo     = (const float*)d_in[9];

    const int n = in_sizes[0] / 3;

    setup_weights<<<(SETUP_TOTAL + 255) / 256, 256, 0, stream>>>(
        w0, s0, b0, wh, sh, bh, wo, so, (unsigned char*)d_ws);

    const int grid = (n + 127) / 128;  // 128 points per block (4 waves x 32)
    mlp_mfma<<<grid, 256, 0, stream>>>(
        points, (const unsigned char*)d_ws, bo, (float*)d_out, n);
}

// Round 4
// 132.113 us; speedup vs baseline: 7.6208x; 1.3231x over previous
//
#include <hip/hip_runtime.h>

// ImplicitFunction MLP via fp16 MFMA (v_mfma_f32_32x32x16_f16), round 4.
// (Round 3 failed to compile: ROCm 7.2 __hmax2 overload bug. Replaced with
//  native _Float16 vector ops + __builtin_elementwise_max -> v_pk_max_f16.)
//
// Activations carried scaled by 1/64 (lrelu is positively homogeneous).
// Key tricks:
//  - K-permuted weights: next layer's A-fragment k-axis is permuted so each
//    lane's B-frag for K-step s is its own two local C-output quads:
//      feat(s,h,j) = 16s + 8*(j>>2) + 4h + (j&3)   (bijection over 0..63)
//    -> zero cross-lane exchange between layers.
//  - Bias in MFMA C-operand (pre-arranged C-layout in LDS, broadcast reads).
//  - lrelu in packed fp16 (v_pk_mul_f16 + v_pk_max_f16) after cvt_pkrtz.
//  - 64 points/wave (2 N-tiles) sharing W-frags and bias C-regs.
//
// Layouts (gfx950, 32x32x16):
//   A/B frag: lane (i=lane&31, h=lane>>5) holds k = 8h+j, j=0..7
//   C/D:      col n = lane&31, row m = (r&3) + 8*(r>>2) + 4h, r=0..15

typedef _Float16 half8 __attribute__((ext_vector_type(8)));
typedef _Float16 half2v __attribute__((ext_vector_type(2)));
typedef float floatx16 __attribute__((ext_vector_type(16)));

#define N_HID 6
// ws / LDS byte offsets (single contiguous image, staged wholesale)
#define OFF_A 0        // hidden W frags [l:6][t:2][s:4][lane:64][j:8] fp16 = 49152
#define OFF_B 49152    // layer0 A frags [t:2][lane:64][j:8] fp16          = 2048
#define OFF_C 51200    // bias/64 fp32, C-layout [l:7][h:2][t:2][r:16]     = 1792
#define OFF_D 52992    // wo*so*64 fp32, C-layout [h:2][t:2][r:16]         = 256
#define IMG_BYTES 53248
#define SETUP_TOTAL (24576 + 1024 + 448 + 64)

__global__ __launch_bounds__(256) void setup_weights(
    const float* __restrict__ w0, const float* __restrict__ s0, const float* __restrict__ b0,
    const float* __restrict__ wh, const float* __restrict__ sh, const float* __restrict__ bh,
    const float* __restrict__ wo, const float* __restrict__ so,
    unsigned char* __restrict__ ws)
{
    int i = blockIdx.x * 256 + threadIdx.x;
    if (i < 24576) {
        // hidden W frags with K-permutation baked in:
        // A[m][kslot(s,h,j)] = wh[l][feat][m] * sh[l][m], feat = 16s+8*(j>>2)+4h+(j&3)
        int j = i & 7, lane = (i >> 3) & 63, s = (i >> 9) & 3, t = (i >> 11) & 1, l = i >> 12;
        int m = 32 * t + (lane & 31);
        int h = lane >> 5;
        int feat = 16 * s + 8 * (j >> 2) + 4 * h + (j & 3);
        ((_Float16*)(ws + OFF_A))[i] = (_Float16)(wh[(l * 64 + feat) * 64 + m] * sh[l * 64 + m]);
    } else if (i < 24576 + 1024) {
        // layer-0 A frags (standard k order; B built from raw points)
        int i2 = i - 24576;
        int j = i2 & 7, lane = (i2 >> 3) & 63, t = i2 >> 9;
        int m = 32 * t + (lane & 31);
        int k = 8 * (lane >> 5) + j;
        float v = (k < 3) ? w0[k * 64 + m] * s0[m] * 0.015625f : 0.f;
        ((_Float16*)(ws + OFF_B))[i2] = (_Float16)v;
    } else if (i < 24576 + 1024 + 448) {
        // biases/64 in C layout
        int i2 = i - 24576 - 1024;
        int r = i2 & 15, t = (i2 >> 4) & 1, h = (i2 >> 5) & 1, l = i2 >> 6;
        int feat = 32 * t + (r & 3) + 8 * ((r >> 2) & 3) + 4 * h;
        float bv = (l == 0) ? b0[feat] : bh[(l - 1) * 64 + feat];
        ((float*)(ws + OFF_C))[i2] = bv * 0.015625f;
    } else if (i < SETUP_TOTAL) {
        // wo*so*64 in C layout
        int i2 = i - 24576 - 1024 - 448;
        int r = i2 & 15, t = (i2 >> 4) & 1, h = i2 >> 5;
        int feat = 32 * t + (r & 3) + 8 * ((r >> 2) & 3) + 4 * h;
        ((float*)(ws + OFF_D))[i2] = wo[feat] * so[0] * 64.f;
    }
}

union FragU { int i[4]; half8 v; };

static __device__ __forceinline__ int pkrtz(float a, float b) {
    auto hh = __builtin_amdgcn_cvt_pkrtz(a, b);  // v2f16, RTZ pack
    int r;
    __builtin_memcpy(&r, &hh, 4);
    return r;
}

// packed-fp16 leaky relu on a pair: max(u, 0.2*u) -> v_pk_mul_f16 + v_pk_max_f16
static __device__ __forceinline__ int lrelu2(int v) {
    half2v u;
    __builtin_memcpy(&u, &v, 4);
    half2v w = u * (_Float16)0.2f;
    half2v r = __builtin_elementwise_max(u, w);
    int o;
    __builtin_memcpy(&o, &r, 4);
    return o;
}

static __device__ __forceinline__ floatx16 mfma16(half8 a, half8 b, floatx16 c) {
    return __builtin_amdgcn_mfma_f32_32x32x16_f16(a, b, c, 0, 0, 0);
}

__global__ __launch_bounds__(256, 3) void mlp_mfma(
    const float* __restrict__ points,
    const unsigned char* __restrict__ ws,
    const float* __restrict__ bo,
    float* __restrict__ out, int n)
{
    __shared__ __align__(16) unsigned char lds[IMG_BYTES];

    // stage full weight image to LDS (53248 B = 13 * 256 * 16)
    {
        const uint4* src = (const uint4*)ws;
        uint4* dst = (uint4*)lds;
#pragma unroll
        for (int i = 0; i < 13; ++i) {
            int idx = threadIdx.x + 256 * i;
            dst[idx] = src[idx];
        }
    }
    __syncthreads();

    const int lane = threadIdx.x & 63;
    const int wv = threadIdx.x >> 6;
    const int p = lane & 31;
    const int h = lane >> 5;
    const int base = (blockIdx.x * 4 + wv) * 64;
    const int pt0 = base + p, pt1 = base + 32 + p;
    const int pl0 = min(pt0, n - 1), pl1 = min(pt1, n - 1);

    const half8* Wf = (const half8*)(lds + OFF_A);          // [l][t][s][lane]
    const half8* A0 = (const half8*)(lds + OFF_B);          // [t][lane]
    const floatx16* biasC = (const floatx16*)(lds + OFF_C); // [(l*2+h)*2+t]
    const floatx16* woC = (const floatx16*)(lds + OFF_D);   // [h*2+t]

    floatx16 acc[2][2];   // [ntile][mtile]
    int fr[2][16];        // packed activations, index 8t + 2*(r>>2) + ((r>>1)&1)

    // ---- layer 0 ----
    {
        FragU bu0, bu1;
        bu0.i[0] = bu0.i[1] = bu0.i[2] = bu0.i[3] = 0;
        bu1 = bu0;
        if (h == 0) {
            bu0.v[0] = (_Float16)points[3 * pl0 + 0];
            bu0.v[1] = (_Float16)points[3 * pl0 + 1];
            bu0.v[2] = (_Float16)points[3 * pl0 + 2];
            bu1.v[0] = (_Float16)points[3 * pl1 + 0];
            bu1.v[1] = (_Float16)points[3 * pl1 + 1];
            bu1.v[2] = (_Float16)points[3 * pl1 + 2];
        }
        floatx16 c0 = biasC[h * 2 + 0];   // l = 0
        floatx16 c1 = biasC[h * 2 + 1];
        half8 a0 = A0[lane], a1 = A0[64 + lane];
        acc[0][0] = mfma16(a0, bu0.v, c0);
        acc[0][1] = mfma16(a1, bu0.v, c1);
        acc[1][0] = mfma16(a0, bu1.v, c0);
        acc[1][1] = mfma16(a1, bu1.v, c1);
    }

    // pack + lrelu -> fr (also the next layer's B-frags, exchange-free)
    auto packfr = [&]() {
#pragma unroll
        for (int nt = 0; nt < 2; ++nt)
#pragma unroll
            for (int t = 0; t < 2; ++t)
#pragma unroll
                for (int rp = 0; rp < 8; ++rp) {
                    int v = pkrtz(acc[nt][t][2 * rp], acc[nt][t][2 * rp + 1]);
                    fr[nt][8 * t + 2 * (rp >> 1) + (rp & 1)] = lrelu2(v);
                }
    };
    packfr();

    // ---- 6 hidden layers ----
    for (int l = 0; l < N_HID; ++l) {
        floatx16 c0 = biasC[((l + 1) * 2 + h) * 2 + 0];
        floatx16 c1 = biasC[((l + 1) * 2 + h) * 2 + 1];
        floatx16 a00 = c0, a01 = c1, a10 = c0, a11 = c1;
        const half8* wl = Wf + l * 512 + lane;  // + t*256 + s*64
#pragma unroll
        for (int s = 0; s < 4; ++s) {
            half8 wt0 = wl[s * 64];
            half8 wt1 = wl[256 + s * 64];
            FragU f0, f1;
#pragma unroll
            for (int c = 0; c < 4; ++c) { f0.i[c] = fr[0][4 * s + c]; f1.i[c] = fr[1][4 * s + c]; }
            a00 = mfma16(wt0, f0.v, a00);
            a01 = mfma16(wt1, f0.v, a01);
            a10 = mfma16(wt0, f1.v, a10);
            a11 = mfma16(wt1, f1.v, a11);
        }
        acc[0][0] = a00; acc[0][1] = a01; acc[1][0] = a10; acc[1][1] = a11;
        if (l < N_HID - 1) packfr();
    }

    // ---- output layer: fp32 lrelu + dot with wo (C-layout), cross-half reduce ----
    {
        floatx16 wo0 = woC[h * 2 + 0];
        floatx16 wo1 = woC[h * 2 + 1];
        float part0 = 0.f, part1 = 0.f;
#pragma unroll
        for (int r = 0; r < 16; ++r) {
            float u;
            u = acc[0][0][r]; part0 = fmaf(fmaxf(u, 0.2f * u), wo0[r], part0);
            u = acc[0][1][r]; part0 = fmaf(fmaxf(u, 0.2f * u), wo1[r], part0);
            u = acc[1][0][r]; part1 = fmaf(fmaxf(u, 0.2f * u), wo0[r], part1);
            u = acc[1][1][r]; part1 = fmaf(fmaxf(u, 0.2f * u), wo1[r], part1);
        }
        part0 += __shfl_xor(part0, 32);
        part1 += __shfl_xor(part1, 32);
        const float bov = bo[0];
        if (h == 0) {
            if (pt0 < n) out[pt0] = part0 + bov;
            if (pt1 < n) out[pt1] = part1 + bov;
        }
    }
}

extern "C" void kernel_launch(void* const* d_in, const int* in_sizes, int n_in,
                              void* d_out, int out_size, void* d_ws, size_t ws_size,
                              hipStream_t stream) {
    const float* points = (const float*)d_in[0];
    const float* w0     = (const float*)d_in[1];
    const float* s0     = (const float*)d_in[2];
    const float* b0     = (const float*)d_in[3];
    const float* wh     = (const float*)d_in[4];
    const float* sh     = (const float*)d_in[5];
    const float* bh     = (const float*)d_in[6];
    const float* wo     = (const float*)d_in[7];
    const float* so     = (const float*)d_in[8];
    const float* bo     = (const float*)d_in[9];

    const int n = in_sizes[0] / 3;

    setup_weights<<<(SETUP_TOTAL + 255) / 256, 256, 0, stream>>>(
        w0, s0, b0, wh, sh, bh, wo, so, (unsigned char*)d_ws);

    const int grid = (n + 255) / 256;  // 256 points per block (4 waves x 64)
    mlp_mfma<<<grid, 256, 0, stream>>>(
        points, (const unsigned char*)d_ws, bo, (float*)d_out, n);
}